// Round 2
// baseline (2990.429 us; speedup 1.0000x reference)
//
#include <hip/hip_runtime.h>
#include <hip/hip_bf16.h>
#include <math.h>

// ---------------- problem constants ----------------
#define BATCH   64
#define NPATCH  196
#define DIM     768
#define DEPTH   6
#define HEADS   12
#define DHEAD   64
#define MLPDIM  3072
#define NMASK   98
#define TOKENS  (BATCH*NPATCH)      // 12544
#define MROWS   (BATCH*NMASK)       // 6272
#define HALFROWS (TOKENS/2)         // 6272

using bf16_t = __hip_bfloat16;
typedef short bf16x8 __attribute__((ext_vector_type(8)));
typedef short short4v __attribute__((ext_vector_type(4)));
typedef float floatx4 __attribute__((ext_vector_type(4)));

__device__ inline float gelu_f(float v) {
    const float c = 0.7978845608028654f;
    float t = tanhf(c * (v + 0.044715f * v * v * v));
    return 0.5f * v * (1.0f + t);
}

__device__ __forceinline__ short f2bf_s(float f) {
    bf16_t t = __float2bfloat16(f);
    return *reinterpret_cast<short*>(&t);
}

__device__ __forceinline__ void gload_lds16(const bf16_t* g, bf16_t* l) {
    __builtin_amdgcn_global_load_lds(
        (const __attribute__((address_space(1))) unsigned int*)g,
        (__attribute__((address_space(3))) unsigned int*)l, 16, 0, 0);
}

// ---------------- bf16 MFMA GEMM: C = A(MxK) @ BT(NxK)^T + bias ----------------
// MODE 0: bias -> fp32   MODE 1: bias+gelu -> bf16   MODE 2: bias+residual -> fp32
// MODE 3: bias -> bf16
// 2-phase double-buffered pipeline (T3-minimum, catalog recipe):
//   prologue: STAGE(buf0,t0); vmcnt(0); barrier
//   loop:     STAGE(buf^1,t+1); compute(buf); vmcnt(0); barrier; flip
// -> next tile's 8 global_load_lds stay in flight across the whole MFMA
//    cluster; the end-of-tile drain only pays the uncovered remainder.
// Raw s_barrier (NOT __syncthreads) so the compiler doesn't insert its own
// full drain before the barrier.
// XCD-chunked bijective block swizzle (m204): contiguous row-major wgid
// ranges per XCD -> consecutive blocks sharing an A-panel land on the same
// XCD's L2 (attacks the 2.1x FETCH over-read seen in round-1 counters).
// LDS K-chunk XOR swizzle: chunk c of row r stored at slot c ^ (r&7).
template<int MODE>
__global__ __launch_bounds__(256) void mm_bf16(
    const bf16_t* __restrict__ A, const bf16_t* __restrict__ BT,
    const float* __restrict__ bias, const float* __restrict__ Cin,
    void* __restrict__ Cout, int M, int N, int K)
{
    __shared__ __align__(16) bf16_t As[2][128 * 64];
    __shared__ __align__(16) bf16_t Bs[2][128 * 64];

    const int tid  = threadIdx.x;
    const int lane = tid & 63;
    const int wave = tid >> 6;
    const int wm = (wave >> 1) * 64;
    const int wn = (wave & 1) * 64;

    // ---- bijective XCD swizzle (m204) ----
    const int gx  = gridDim.x;
    const int nwg = gx * gridDim.y;
    const int orig = blockIdx.y * gx + blockIdx.x;
    const int qq = nwg >> 3, rr = nwg & 7;
    const int xcd = orig & 7, seq = orig >> 3;
    const int wg = (xcd < rr ? xcd * (qq + 1) : rr * (qq + 1) + (xcd - rr) * qq) + seq;
    const int m0 = (wg / gx) * 128;
    const int n0 = (wg % gx) * 128;

    // staging: LDS slot tid*8 holds (row tid>>3, slot tid&7); fetch global
    // chunk (tid&7) ^ (row&7) so slot p of row r holds chunk p ^ (r&7).
    const int srow = tid >> 3;
    const int schunk = (tid & 7) ^ (srow & 7);
    const bf16_t* gA = A  + (size_t)(m0 + srow) * K + schunk * 8;
    const bf16_t* gB = BT + (size_t)(n0 + srow) * K + schunk * 8;
    const int lds_off = tid * 8;

    floatx4 acc[4][4];
#pragma unroll
    for (int i = 0; i < 4; ++i)
#pragma unroll
        for (int j = 0; j < 4; ++j) acc[i][j] = (floatx4)0.0f;

    const int quad = lane >> 4;
    const int rm = lane & 15;
    const int nt = K >> 6;

    // ---- prologue: stage tile 0 into buf 0 ----
#pragma unroll
    for (int i = 0; i < 4; ++i) {
        gload_lds16(gA + (size_t)(32 * i) * K, &As[0][lds_off] + i * 2048);
        gload_lds16(gB + (size_t)(32 * i) * K, &Bs[0][lds_off] + i * 2048);
    }
    asm volatile("s_waitcnt vmcnt(0)" ::: "memory");
    __builtin_amdgcn_s_barrier();
    asm volatile("" ::: "memory");

    int cur = 0;
    for (int t = 0; t < nt; ++t) {
        const bf16_t* sA = cur ? &As[1][0] : &As[0][0];
        const bf16_t* sB = cur ? &Bs[1][0] : &Bs[0][0];
        if (t + 1 < nt) {
            bf16_t* dA = cur ? &As[0][lds_off] : &As[1][lds_off];
            bf16_t* dB = cur ? &Bs[0][lds_off] : &Bs[1][lds_off];
            const int koff = (t + 1) * 64;
#pragma unroll
            for (int i = 0; i < 4; ++i) {
                gload_lds16(gA + koff + (size_t)(32 * i) * K, dA + i * 2048);
                gload_lds16(gB + koff + (size_t)(32 * i) * K, dB + i * 2048);
            }
        }

#pragma unroll
        for (int kk = 0; kk < 2; ++kk) {
            const int kq = (((kk << 2) | quad) ^ (rm & 7)) * 8;
            bf16x8 a[4], b[4];
#pragma unroll
            for (int mi = 0; mi < 4; ++mi)
                a[mi] = *(const bf16x8*)&sA[(wm + mi * 16 + rm) * 64 + kq];
#pragma unroll
            for (int ni = 0; ni < 4; ++ni)
                b[ni] = *(const bf16x8*)&sB[(wn + ni * 16 + rm) * 64 + kq];
#pragma unroll
            for (int mi = 0; mi < 4; ++mi)
#pragma unroll
                for (int ni = 0; ni < 4; ++ni)
                    acc[mi][ni] = __builtin_amdgcn_mfma_f32_16x16x32_bf16(
                        a[mi], b[ni], acc[mi][ni], 0, 0, 0);
        }

        if (t + 1 < nt) {
            asm volatile("s_waitcnt vmcnt(0)" ::: "memory");
            __builtin_amdgcn_s_barrier();
            asm volatile("" ::: "memory");
            cur ^= 1;
        }
    }

    const int cm = m0 + wm + quad * 4;
    const int cn = n0 + wn + rm;
#pragma unroll
    for (int mi = 0; mi < 4; ++mi) {
#pragma unroll
        for (int ni = 0; ni < 4; ++ni) {
#pragma unroll
            for (int r = 0; r < 4; ++r) {
                const int row = cm + mi * 16 + r;
                const int col = cn + ni * 16;
                float v = acc[mi][ni][r] + bias[col];
                const size_t idx = (size_t)row * N + col;
                if (MODE == 0) {
                    ((float*)Cout)[idx] = v;
                } else if (MODE == 1) {
                    ((bf16_t*)Cout)[idx] = __float2bfloat16(gelu_f(v));
                } else if (MODE == 2) {
                    ((float*)Cout)[idx] = v + Cin[idx];
                } else {
                    ((bf16_t*)Cout)[idx] = __float2bfloat16(v);
                }
            }
        }
    }
}

// ---------------- weight convert + transpose ----------------
__global__ __launch_bounds__(256) void wconvT(
    const float* __restrict__ W, bf16_t* __restrict__ WT, int K, int N)
{
    __shared__ float t[32][33];
    const size_t off = (size_t)blockIdx.z * K * N;
    const int k0 = blockIdx.y * 32, n0 = blockIdx.x * 32;
    const int r = threadIdx.x >> 5, c = threadIdx.x & 31;
#pragma unroll
    for (int i = 0; i < 4; ++i)
        t[r + i * 8][c] = W[off + (size_t)(k0 + r + i * 8) * N + n0 + c];
    __syncthreads();
#pragma unroll
    for (int i = 0; i < 4; ++i)
        WT[off + (size_t)(n0 + r + i * 8) * K + k0 + c] =
            __float2bfloat16(t[c][r + i * 8]);
}

// ---------------- patchify ----------------
__global__ __launch_bounds__(256) void patchify_kernel(
    const float* __restrict__ img, bf16_t* __restrict__ patches)
{
    const int row = blockIdx.x;
    const int b = row / NPATCH, p = row % NPATCH;
    const int gy = p / 14, gx = p % 14;
    for (int e = threadIdx.x; e < 768; e += 256) {
        const int c = e % 3, pix = e / 3;
        const int py = pix / 16, px = pix % 16;
        const size_t src = (((size_t)b * 224 + gy * 16 + py) * 224 + gx * 16 + px) * 3 + c;
        patches[(size_t)row * 768 + e] = __float2bfloat16(img[src]);
    }
}

// ---------------- mask top-k ----------------
__global__ __launch_bounds__(256) void mask_kernel(
    const float* __restrict__ noise, int* __restrict__ flags, int* __restrict__ midx)
{
    const int b = blockIdx.x;
    __shared__ float v[NPATCH];
    const int t = threadIdx.x;
    if (t < NPATCH) v[t] = noise[b * NPATCH + t];
    __syncthreads();
    if (t < NPATCH) {
        const float mine = v[t];
        int r = 0;
        for (int j = 0; j < NPATCH; ++j) {
            const float o = v[j];
            r += (o > mine) || (o == mine && j < t);
        }
        const int f = (r < NMASK) ? 1 : 0;
        flags[b * NPATCH + t] = f;
        if (f) midx[b * NMASK + r] = t;
    }
}

// ---------------- pos-emb add + mask-token substitute ----------------
__global__ __launch_bounds__(256) void pe_mask_kernel(
    float* __restrict__ x, const float* __restrict__ pos_emb,
    const float* __restrict__ mask_token, const int* __restrict__ flags)
{
    const int wave = threadIdx.x >> 6, lane = threadIdx.x & 63;
    const int row = blockIdx.x * 4 + wave;
    const int n = row % NPATCH;
    const int masked = flags[row];
    const float* pe = pos_emb + (size_t)(n + 1) * 768;
    float* xr = x + (size_t)row * 768;
#pragma unroll
    for (int j = 0; j < 3; ++j) {
        const int off = j * 256 + lane * 4;
        const float4 pev = *(const float4*)(pe + off);
        float4 o;
        if (masked) {
            const float4 mt = *(const float4*)(mask_token + off);
            o.x = mt.x + pev.x; o.y = mt.y + pev.y;
            o.z = mt.z + pev.z; o.w = mt.w + pev.w;
        } else {
            const float4 xv = *(const float4*)(xr + off);
            o.x = xv.x + pev.x; o.y = xv.y + pev.y;
            o.z = xv.z + pev.z; o.w = xv.w + pev.w;
        }
        *(float4*)(xr + off) = o;
    }
}

// ---------------- layernorm ----------------
__global__ __launch_bounds__(256) void ln_kernel(
    const float* __restrict__ x, bf16_t* __restrict__ out,
    const float* __restrict__ s, const float* __restrict__ bvec)
{
    const int wave = threadIdx.x >> 6, lane = threadIdx.x & 63;
    const int row = blockIdx.x * 4 + wave;
    const float* xr = x + (size_t)row * 768;

    float4 v[3];
    float sum = 0.0f, sq = 0.0f;
#pragma unroll
    for (int j = 0; j < 3; ++j) {
        v[j] = *(const float4*)(xr + j * 256 + lane * 4);
        sum += v[j].x + v[j].y + v[j].z + v[j].w;
        sq  += v[j].x * v[j].x + v[j].y * v[j].y + v[j].z * v[j].z + v[j].w * v[j].w;
    }
#pragma unroll
    for (int off = 32; off; off >>= 1) {
        sum += __shfl_xor(sum, off, 64);
        sq  += __shfl_xor(sq, off, 64);
    }
    const float mean = sum * (1.0f / 768.0f);
    const float var = sq * (1.0f / 768.0f) - mean * mean;
    const float inv = rsqrtf(var + 1e-5f);

    bf16_t* orow = out + (size_t)row * 768;
#pragma unroll
    for (int j = 0; j < 3; ++j) {
        const int off = j * 256 + lane * 4;
        const float4 sv = *(const float4*)(s + off);
        const float4 bv = *(const float4*)(bvec + off);
        short4v o;
        o[0] = f2bf_s((v[j].x - mean) * inv * sv.x + bv.x);
        o[1] = f2bf_s((v[j].y - mean) * inv * sv.y + bv.y);
        o[2] = f2bf_s((v[j].z - mean) * inv * sv.z + bv.z);
        o[3] = f2bf_s((v[j].w - mean) * inv * sv.w + bv.w);
        *(short4v*)(orow + off) = o;
    }
}

// ---------------- MFMA flash attention ----------------
__global__ __launch_bounds__(256) void attn_kernel(
    const bf16_t* __restrict__ qkv, bf16_t* __restrict__ out)
{
    const int bh = blockIdx.x;
    const int b = bh / HEADS, h = bh % HEADS;
    const int tid = threadIdx.x, lane = tid & 63, wave = tid >> 6;
    const int quad = lane >> 4, l16 = lane & 15;
    const int wq = wave * 64;

    __shared__ __align__(16) short Vt[64][68];
    __shared__ __align__(16) short Plds[4][64][68];
    __shared__ float red[4][64];

    const size_t tok0 = (size_t)b * NPATCH;
    const int hoff = h * 64;

    bf16x8 qf[4][2];
#pragma unroll
    for (int ni = 0; ni < 4; ++ni) {
        const int q = wq + ni * 16 + l16;
        const int qe = q < 195 ? q : 195;
#pragma unroll
        for (int ks = 0; ks < 2; ++ks)
            qf[ni][ks] = *(const bf16x8*)(qkv + (tok0 + qe) * 2304 + hoff + ks * 32 + quad * 8);
    }

    floatx4 accO[4][4];
#pragma unroll
    for (int i = 0; i < 4; ++i)
#pragma unroll
        for (int j = 0; j < 4; ++j) accO[i][j] = (floatx4)0.0f;
    float mrun[4], lrun[4];
#pragma unroll
    for (int ni = 0; ni < 4; ++ni) { mrun[ni] = -1e30f; lrun[ni] = 0.0f; }

    for (int kc = 0; kc < 256; kc += 64) {
        __syncthreads();
        {
            const int kl = tid & 63;
            const int dg = tid >> 6;
            const int key = kc + kl;
            if (key < NPATCH) {
                const bf16_t* src = qkv + (tok0 + key) * 2304 + 1536 + hoff + dg * 16;
                bf16x8 v0 = *(const bf16x8*)src;
                bf16x8 v1 = *(const bf16x8*)(src + 8);
#pragma unroll
                for (int j = 0; j < 8; ++j) {
                    Vt[dg * 16 + j][kl]     = v0[j];
                    Vt[dg * 16 + 8 + j][kl] = v1[j];
                }
            } else {
#pragma unroll
                for (int j = 0; j < 16; ++j) Vt[dg * 16 + j][kl] = 0;
            }
        }
        __syncthreads();

        bf16x8 af[4][2];
#pragma unroll
        for (int mi = 0; mi < 4; ++mi) {
            const int key = kc + mi * 16 + l16;
            const int ke = key < 195 ? key : 195;
#pragma unroll
            for (int ks = 0; ks < 2; ++ks)
                af[mi][ks] = *(const bf16x8*)(qkv + (tok0 + ke) * 2304 + 768 + hoff + ks * 32 + quad * 8);
        }
        floatx4 accS[4][4];
#pragma unroll
        for (int i = 0; i < 4; ++i)
#pragma unroll
            for (int j = 0; j < 4; ++j) accS[i][j] = (floatx4)0.0f;
#pragma unroll
        for (int mi = 0; mi < 4; ++mi)
#pragma unroll
            for (int ni = 0; ni < 4; ++ni)
#pragma unroll
                for (int ks = 0; ks < 2; ++ks)
                    accS[mi][ni] = __builtin_amdgcn_mfma_f32_16x16x32_bf16(
                        af[mi][ks], qf[ni][ks], accS[mi][ni], 0, 0, 0);

#pragma unroll
        for (int mi = 0; mi < 4; ++mi) {
#pragma unroll
            for (int r = 0; r < 4; ++r) {
                const int key = kc + mi * 16 + quad * 4 + r;
                const bool valid = key < NPATCH;
#pragma unroll
                for (int ni = 0; ni < 4; ++ni)
                    accS[mi][ni][r] = valid ? accS[mi][ni][r] * 0.125f : -1e30f;
            }
        }

        float alpha[4];
#pragma unroll
        for (int ni = 0; ni < 4; ++ni) {
            float mx = -1e30f;
#pragma unroll
            for (int mi = 0; mi < 4; ++mi)
#pragma unroll
                for (int r = 0; r < 4; ++r) mx = fmaxf(mx, accS[mi][ni][r]);
            mx = fmaxf(mx, __shfl_xor(mx, 16, 64));
            mx = fmaxf(mx, __shfl_xor(mx, 32, 64));
            const float mnew = fmaxf(mrun[ni], mx);
            float s = 0.0f;
#pragma unroll
            for (int mi = 0; mi < 4; ++mi)
#pragma unroll
                for (int r = 0; r < 4; ++r) {
                    const float p = __expf(accS[mi][ni][r] - mnew);
                    accS[mi][ni][r] = p;
                    s += p;
                }
            s += __shfl_xor(s, 16, 64);
            s += __shfl_xor(s, 32, 64);
            alpha[ni] = __expf(mrun[ni] - mnew);
            lrun[ni] = lrun[ni] * alpha[ni] + s;
            mrun[ni] = mnew;
        }
        if (quad == 0) {
#pragma unroll
            for (int ni = 0; ni < 4; ++ni) red[wave][ni * 16 + l16] = alpha[ni];
        }

#pragma unroll
        for (int mi = 0; mi < 4; ++mi)
#pragma unroll
            for (int ni = 0; ni < 4; ++ni) {
                short4v pk;
#pragma unroll
                for (int r = 0; r < 4; ++r) pk[r] = f2bf_s(accS[mi][ni][r]);
                *(short4v*)&Plds[wave][ni * 16 + l16][mi * 16 + quad * 4] = pk;
            }
        asm volatile("s_waitcnt lgkmcnt(0)" ::: "memory");

#pragma unroll
        for (int mi = 0; mi < 4; ++mi) {
            const float4 al = *(const float4*)&red[wave][mi * 16 + quad * 4];
#pragma unroll
            for (int ni = 0; ni < 4; ++ni) {
                accO[mi][ni][0] *= al.x;
                accO[mi][ni][1] *= al.y;
                accO[mi][ni][2] *= al.z;
                accO[mi][ni][3] *= al.w;
            }
        }

#pragma unroll
        for (int ks = 0; ks < 2; ++ks) {
            bf16x8 pa[4], vb[4];
#pragma unroll
            for (int mi = 0; mi < 4; ++mi) {
                short4v lo = *(const short4v*)&Plds[wave][mi * 16 + l16][ks * 32 + quad * 8];
                short4v hi = *(const short4v*)&Plds[wave][mi * 16 + l16][ks * 32 + quad * 8 + 4];
                pa[mi] = __builtin_shufflevector(lo, hi, 0, 1, 2, 3, 4, 5, 6, 7);
            }
#pragma unroll
            for (int ni = 0; ni < 4; ++ni) {
                short4v lo = *(const short4v*)&Vt[ni * 16 + l16][ks * 32 + quad * 8];
                short4v hi = *(const short4v*)&Vt[ni * 16 + l16][ks * 32 + quad * 8 + 4];
                vb[ni] = __builtin_shufflevector(lo, hi, 0, 1, 2, 3, 4, 5, 6, 7);
            }
#pragma unroll
            for (int mi = 0; mi < 4; ++mi)
#pragma unroll
                for (int ni = 0; ni < 4; ++ni)
                    accO[mi][ni] = __builtin_amdgcn_mfma_f32_16x16x32_bf16(
                        pa[mi], vb[ni], accO[mi][ni], 0, 0, 0);
        }
    }

    if (quad == 0) {
#pragma unroll
        for (int ni = 0; ni < 4; ++ni) red[wave][ni * 16 + l16] = lrun[ni];
    }
    asm volatile("s_waitcnt lgkmcnt(0)" ::: "memory");
#pragma unroll
    for (int mi = 0; mi < 4; ++mi) {
        const float4 lv = *(const float4*)&red[wave][mi * 16 + quad * 4];
        const float inv[4] = {1.0f / lv.x, 1.0f / lv.y, 1.0f / lv.z, 1.0f / lv.w};
#pragma unroll
        for (int r = 0; r < 4; ++r) {
            const int q = wq + mi * 16 + quad * 4 + r;
            if (q < NPATCH) {
#pragma unroll
                for (int ni = 0; ni < 4; ++ni) {
                    const int d = ni * 16 + l16;
                    out[(tok0 + q) * 768 + hoff + d] =
                        __float2bfloat16(accO[mi][ni][r] * inv[r]);
                }
            }
        }
    }
}

// ---------------- gather masked rows ----------------
__global__ __launch_bounds__(256) void gather_kernel(
    const float* __restrict__ x, const int* __restrict__ midx, bf16_t* __restrict__ em)
{
    const int row = blockIdx.x;
    const int b = row / NMASK;
    const int n = midx[row];
    const float* src = x + (size_t)(b * NPATCH + n) * 768;
    bf16_t* dst = em + (size_t)row * 768;
    for (int e = threadIdx.x; e < 768; e += 256) dst[e] = __float2bfloat16(src[e]);
}

__global__ void zero_kernel(float* __restrict__ p) {
    if (threadIdx.x == 0 && blockIdx.x == 0) p[0] = 0.0f;
}

// ---------------- L1 loss ----------------
__global__ __launch_bounds__(256) void loss_kernel(
    const float* __restrict__ pred, const float* __restrict__ img,
    const int* __restrict__ midx, float* __restrict__ acc)
{
    const size_t total = (size_t)MROWS * 768;
    float part = 0.0f;
    for (size_t idx = (size_t)blockIdx.x * blockDim.x + threadIdx.x; idx < total;
         idx += (size_t)gridDim.x * blockDim.x) {
        const int e = (int)(idx % 768);
        const int row = (int)(idx / 768);
        const int b = row / NMASK;
        const int n = midx[row];
        const int c = e % 3, pix = e / 3;
        const int py = pix / 16, px = pix % 16;
        const int gy = n / 14, gx = n % 14;
        const float ref =
            img[(((size_t)b * 224 + gy * 16 + py) * 224 + gx * 16 + px) * 3 + c];
        part += fabsf(pred[idx] - ref);
    }
#pragma unroll
    for (int off = 32; off; off >>= 1) part += __shfl_down(part, off, 64);
    __shared__ float sp[4];
    if ((threadIdx.x & 63) == 0) sp[threadIdx.x >> 6] = part;
    __syncthreads();
    if (threadIdx.x == 0) atomicAdd(acc, sp[0] + sp[1] + sp[2] + sp[3]);
}

__global__ void finalize_kernel(const float* __restrict__ acc, float* __restrict__ out)
{
    if (threadIdx.x == 0 && blockIdx.x == 0)
        out[0] = acc[0] * (float)(1.0 / 472055808.0);   // 1/(64*98*768*98)
}

// ---------------- launch ----------------
extern "C" void kernel_launch(void* const* d_in, const int* in_sizes, int n_in,
                              void* d_out, int out_size, void* d_ws, size_t ws_size,
                              hipStream_t stream)
{
    const float* img      = (const float*)d_in[0];
    const float* noise    = (const float*)d_in[1];
    const float* patch_w  = (const float*)d_in[2];
    const float* patch_b  = (const float*)d_in[3];
    const float* pos_emb  = (const float*)d_in[4];
    const float* mask_tok = (const float*)d_in[5];
    const float* ln1_s    = (const float*)d_in[6];
    const float* ln1_b    = (const float*)d_in[7];
    const float* wqkv     = (const float*)d_in[8];
    const float* bqkv     = (const float*)d_in[9];
    const float* wo       = (const float*)d_in[10];
    const float* bo       = (const float*)d_in[11];
    const float* ln2_s    = (const float*)d_in[12];
    const float* ln2_b    = (const float*)d_in[13];
    const float* w1       = (const float*)d_in[14];
    const float* b1       = (const float*)d_in[15];
    const float* w2       = (const float*)d_in[16];
    const float* b2       = (const float*)d_in[17];
    const float* pix_w    = (const float*)d_in[18];
    const float* pix_b    = (const float*)d_in[19];

    const size_t TOK = (size_t)TOKENS * 768;
    float*  x    = (float*)d_ws;
    bf16_t* h    = (bf16_t*)(x + TOK);
    bf16_t* qbuf = h + TOK;
    bf16_t* wts  = qbuf + (size_t)TOKENS * 2304;
    size_t o = 0;
    bf16_t* patch_wT = wts + o; o += (size_t)768 * 768;
    bf16_t* wqkvT    = wts + o; o += (size_t)DEPTH * 2304 * 768;
    bf16_t* woT      = wts + o; o += (size_t)DEPTH * 768 * 768;
    bf16_t* w1T      = wts + o; o += (size_t)DEPTH * 3072 * 768;
    bf16_t* w2T      = wts + o; o += (size_t)DEPTH * 768 * 3072;
    bf16_t* pix_wT   = wts + o; o += (size_t)768 * 768;
    int* flags = (int*)(wts + o);
    int* midx  = flags + TOKENS;
    float* acc = (float*)(midx + MROWS);

    // optional full-M MLP intermediate (77 MB) if the workspace has room
    size_t used = (size_t)((char*)(acc + 1) - (char*)d_ws);
    used = (used + 255) & ~(size_t)255;
    bf16_t* mlpbuf = (bf16_t*)((char*)d_ws + used);
    const bool fullmlp =
        ws_size >= used + (size_t)TOKENS * MLPDIM * sizeof(bf16_t);

    bf16_t* patches = qbuf;
    float*  pred    = (float*)qbuf;

    wconvT<<<dim3(768/32, 768/32, 1), 256, 0, stream>>>(patch_w, patch_wT, 768, 768);
    wconvT<<<dim3(2304/32, 768/32, DEPTH), 256, 0, stream>>>(wqkv, wqkvT, 768, 2304);
    wconvT<<<dim3(768/32, 768/32, DEPTH), 256, 0, stream>>>(wo, woT, 768, 768);
    wconvT<<<dim3(3072/32, 768/32, DEPTH), 256, 0, stream>>>(w1, w1T, 768, 3072);
    wconvT<<<dim3(768/32, 3072/32, DEPTH), 256, 0, stream>>>(w2, w2T, 3072, 768);
    wconvT<<<dim3(768/32, 768/32, 1), 256, 0, stream>>>(pix_w, pix_wT, 768, 768);

    patchify_kernel<<<TOKENS, 256, 0, stream>>>(img, patches);
    mask_kernel<<<BATCH, 256, 0, stream>>>(noise, flags, midx);

    mm_bf16<0><<<dim3(768/128, TOKENS/128), 256, 0, stream>>>(
        patches, patch_wT, patch_b, nullptr, x, TOKENS, 768, 768);
    pe_mask_kernel<<<TOKENS/4, 256, 0, stream>>>(x, pos_emb, mask_tok, flags);

    for (int l = 0; l < DEPTH; ++l) {
        ln_kernel<<<TOKENS/4, 256, 0, stream>>>(x, h, ln1_s + l * 768, ln1_b + l * 768);
        mm_bf16<3><<<dim3(2304/128, TOKENS/128), 256, 0, stream>>>(
            h, wqkvT + (size_t)l * 2304 * 768, bqkv + l * 2304, nullptr, qbuf,
            TOKENS, 2304, 768);
        attn_kernel<<<BATCH * HEADS, 256, 0, stream>>>(qbuf, h);
        mm_bf16<2><<<dim3(768/128, TOKENS/128), 256, 0, stream>>>(
            h, woT + (size_t)l * 768 * 768, bo + l * 768, x, x, TOKENS, 768, 768);
        ln_kernel<<<TOKENS/4, 256, 0, stream>>>(x, h, ln2_s + l * 768, ln2_b + l * 768);
        if (fullmlp) {
            mm_bf16<1><<<dim3(MLPDIM/128, TOKENS/128), 256, 0, stream>>>(
                h, w1T + (size_t)l * 3072 * 768, b1 + l * MLPDIM, nullptr, mlpbuf,
                TOKENS, MLPDIM, 768);
            mm_bf16<2><<<dim3(768/128, TOKENS/128), 256, 0, stream>>>(
                mlpbuf, w2T + (size_t)l * 768 * 3072, b2 + l * 768, x, x,
                TOKENS, 768, MLPDIM);
        } else {
            for (int ch = 0; ch < 2; ++ch) {
                bf16_t* hA = h + (size_t)ch * HALFROWS * 768;
                float*  xC = x + (size_t)ch * HALFROWS * 768;
                mm_bf16<1><<<dim3(MLPDIM/128, HALFROWS/128), 256, 0, stream>>>(
                    hA, w1T + (size_t)l * 3072 * 768, b1 + l * MLPDIM, nullptr, qbuf,
                    HALFROWS, MLPDIM, 768);
                mm_bf16<2><<<dim3(768/128, HALFROWS/128), 256, 0, stream>>>(
                    qbuf, w2T + (size_t)l * 768 * 3072, b2 + l * 768, xC, xC,
                    HALFROWS, 768, MLPDIM);
            }
        }
    }

    gather_kernel<<<MROWS, 256, 0, stream>>>(x, midx, h);
    mm_bf16<0><<<dim3(768/128, MROWS/128), 256, 0, stream>>>(
        h, pix_wT, pix_b, nullptr, pred, MROWS, 768, 768);

    zero_kernel<<<1, 64, 0, stream>>>(acc);
    loss_kernel<<<4704, 256, 0, stream>>>(pred, img, midx, acc);
    finalize_kernel<<<1, 64, 0, stream>>>(acc, (float*)d_out);
}

// Round 3
// 2939.981 us; speedup vs baseline: 1.0172x; 1.0172x over previous
//
#include <hip/hip_runtime.h>
#include <hip/hip_bf16.h>
#include <math.h>

// ---------------- problem constants ----------------
#define BATCH   64
#define NPATCH  196
#define DIM     768
#define DEPTH   6
#define HEADS   12
#define DHEAD   64
#define MLPDIM  3072
#define NMASK   98
#define TOKENS  (BATCH*NPATCH)      // 12544
#define MROWS   (BATCH*NMASK)       // 6272
#define HALFROWS (TOKENS/2)         // 6272

using bf16_t = __hip_bfloat16;
typedef short bf16x8 __attribute__((ext_vector_type(8)));
typedef short short4v __attribute__((ext_vector_type(4)));
typedef float floatx4 __attribute__((ext_vector_type(4)));

__device__ inline float gelu_f(float v) {
    const float c = 0.7978845608028654f;
    float t = tanhf(c * (v + 0.044715f * v * v * v));
    return 0.5f * v * (1.0f + t);
}

__device__ __forceinline__ short f2bf_s(float f) {
    bf16_t t = __float2bfloat16(f);
    return *reinterpret_cast<short*>(&t);
}

__device__ __forceinline__ void gload_lds16(const bf16_t* g, bf16_t* l) {
    __builtin_amdgcn_global_load_lds(
        (const __attribute__((address_space(1))) unsigned int*)g,
        (__attribute__((address_space(3))) unsigned int*)l, 16, 0, 0);
}

// ---------------- bf16 MFMA GEMM: C = A(MxK) @ BT(NxK)^T + bias ----------------
// MODE 0: bias -> fp32   MODE 1: bias+gelu -> bf16   MODE 2: bias+residual -> fp32
// MODE 3: bias -> bf16
// Single-buffered BK=64, 32 KB LDS -> 4 blocks/CU (round-2 showed the 64 KB
// double-buffer caps large-grid GEMMs at 2 blocks/CU: -570 us net; implicit
// wave-level overlap at 4 blocks/CU beats explicit 2-phase at 2 blocks/CU).
// XCD-chunked bijective block swizzle (m204): halved FETCH_SIZE in round-2
// counters (131.7 -> 58.7 MB on the w2-class GEMM) -> keep.
// LDS K-chunk XOR swizzle: chunk c of row r stored at slot c ^ (r&7)
// -> conflict-free ds_read_b128 fragments.
template<int MODE>
__global__ __launch_bounds__(256) void mm_bf16(
    const bf16_t* __restrict__ A, const bf16_t* __restrict__ BT,
    const float* __restrict__ bias, const float* __restrict__ Cin,
    void* __restrict__ Cout, int M, int N, int K)
{
    __shared__ __align__(16) bf16_t As[128 * 64];
    __shared__ __align__(16) bf16_t Bs[128 * 64];

    const int tid  = threadIdx.x;
    const int lane = tid & 63;
    const int wave = tid >> 6;
    const int wm = (wave >> 1) * 64;
    const int wn = (wave & 1) * 64;

    // ---- bijective XCD swizzle (m204) ----
    const int gx  = gridDim.x;
    const int nwg = gx * gridDim.y;
    const int orig = blockIdx.y * gx + blockIdx.x;
    const int qq = nwg >> 3, rr = nwg & 7;
    const int xcd = orig & 7, seq = orig >> 3;
    const int wg = (xcd < rr ? xcd * (qq + 1) : rr * (qq + 1) + (xcd - rr) * qq) + seq;
    const int m0 = (wg / gx) * 128;
    const int n0 = (wg % gx) * 128;

    // staging: LDS slot tid*8 holds (row tid>>3, slot tid&7); fetch global
    // chunk (tid&7) ^ (row&7) so slot p of row r holds chunk p ^ (r&7).
    const int srow = tid >> 3;
    const int schunk = (tid & 7) ^ (srow & 7);
    const bf16_t* gA = A  + (size_t)(m0 + srow) * K + schunk * 8;
    const bf16_t* gB = BT + (size_t)(n0 + srow) * K + schunk * 8;
    bf16_t* lA = &As[tid * 8];
    bf16_t* lB = &Bs[tid * 8];

    floatx4 acc[4][4];
#pragma unroll
    for (int i = 0; i < 4; ++i)
#pragma unroll
        for (int j = 0; j < 4; ++j) acc[i][j] = (floatx4)0.0f;

    const int quad = lane >> 4;
    const int rm = lane & 15;

    for (int k0 = 0; k0 < K; k0 += 64) {
        __syncthreads();
#pragma unroll
        for (int i = 0; i < 4; ++i) {
            gload_lds16(gA + k0 + (size_t)(32 * i) * K, lA + i * 2048);
            gload_lds16(gB + k0 + (size_t)(32 * i) * K, lB + i * 2048);
        }
        __syncthreads();

#pragma unroll
        for (int kk = 0; kk < 2; ++kk) {
            const int kq = (((kk << 2) | quad) ^ (rm & 7)) * 8;
            bf16x8 a[4], b[4];
#pragma unroll
            for (int mi = 0; mi < 4; ++mi)
                a[mi] = *(const bf16x8*)&As[(wm + mi * 16 + rm) * 64 + kq];
#pragma unroll
            for (int ni = 0; ni < 4; ++ni)
                b[ni] = *(const bf16x8*)&Bs[(wn + ni * 16 + rm) * 64 + kq];
#pragma unroll
            for (int mi = 0; mi < 4; ++mi)
#pragma unroll
                for (int ni = 0; ni < 4; ++ni)
                    acc[mi][ni] = __builtin_amdgcn_mfma_f32_16x16x32_bf16(
                        a[mi], b[ni], acc[mi][ni], 0, 0, 0);
        }
    }

    const int cm = m0 + wm + quad * 4;
    const int cn = n0 + wn + rm;
#pragma unroll
    for (int mi = 0; mi < 4; ++mi) {
#pragma unroll
        for (int ni = 0; ni < 4; ++ni) {
#pragma unroll
            for (int r = 0; r < 4; ++r) {
                const int row = cm + mi * 16 + r;
                const int col = cn + ni * 16;
                float v = acc[mi][ni][r] + bias[col];
                const size_t idx = (size_t)row * N + col;
                if (MODE == 0) {
                    ((float*)Cout)[idx] = v;
                } else if (MODE == 1) {
                    ((bf16_t*)Cout)[idx] = __float2bfloat16(gelu_f(v));
                } else if (MODE == 2) {
                    ((float*)Cout)[idx] = v + Cin[idx];
                } else {
                    ((bf16_t*)Cout)[idx] = __float2bfloat16(v);
                }
            }
        }
    }
}

// ---------------- weight convert + transpose ----------------
__global__ __launch_bounds__(256) void wconvT(
    const float* __restrict__ W, bf16_t* __restrict__ WT, int K, int N)
{
    __shared__ float t[32][33];
    const size_t off = (size_t)blockIdx.z * K * N;
    const int k0 = blockIdx.y * 32, n0 = blockIdx.x * 32;
    const int r = threadIdx.x >> 5, c = threadIdx.x & 31;
#pragma unroll
    for (int i = 0; i < 4; ++i)
        t[r + i * 8][c] = W[off + (size_t)(k0 + r + i * 8) * N + n0 + c];
    __syncthreads();
#pragma unroll
    for (int i = 0; i < 4; ++i)
        WT[off + (size_t)(n0 + r + i * 8) * K + k0 + c] =
            __float2bfloat16(t[c][r + i * 8]);
}

// ---------------- patchify ----------------
__global__ __launch_bounds__(256) void patchify_kernel(
    const float* __restrict__ img, bf16_t* __restrict__ patches)
{
    const int row = blockIdx.x;
    const int b = row / NPATCH, p = row % NPATCH;
    const int gy = p / 14, gx = p % 14;
    for (int e = threadIdx.x; e < 768; e += 256) {
        const int c = e % 3, pix = e / 3;
        const int py = pix / 16, px = pix % 16;
        const size_t src = (((size_t)b * 224 + gy * 16 + py) * 224 + gx * 16 + px) * 3 + c;
        patches[(size_t)row * 768 + e] = __float2bfloat16(img[src]);
    }
}

// ---------------- mask top-k ----------------
__global__ __launch_bounds__(256) void mask_kernel(
    const float* __restrict__ noise, int* __restrict__ flags, int* __restrict__ midx)
{
    const int b = blockIdx.x;
    __shared__ float v[NPATCH];
    const int t = threadIdx.x;
    if (t < NPATCH) v[t] = noise[b * NPATCH + t];
    __syncthreads();
    if (t < NPATCH) {
        const float mine = v[t];
        int r = 0;
        for (int j = 0; j < NPATCH; ++j) {
            const float o = v[j];
            r += (o > mine) || (o == mine && j < t);
        }
        const int f = (r < NMASK) ? 1 : 0;
        flags[b * NPATCH + t] = f;
        if (f) midx[b * NMASK + r] = t;
    }
}

// ---------------- pos-emb add + mask-token substitute ----------------
__global__ __launch_bounds__(256) void pe_mask_kernel(
    float* __restrict__ x, const float* __restrict__ pos_emb,
    const float* __restrict__ mask_token, const int* __restrict__ flags)
{
    const int wave = threadIdx.x >> 6, lane = threadIdx.x & 63;
    const int row = blockIdx.x * 4 + wave;
    const int n = row % NPATCH;
    const int masked = flags[row];
    const float* pe = pos_emb + (size_t)(n + 1) * 768;
    float* xr = x + (size_t)row * 768;
#pragma unroll
    for (int j = 0; j < 3; ++j) {
        const int off = j * 256 + lane * 4;
        const float4 pev = *(const float4*)(pe + off);
        float4 o;
        if (masked) {
            const float4 mt = *(const float4*)(mask_token + off);
            o.x = mt.x + pev.x; o.y = mt.y + pev.y;
            o.z = mt.z + pev.z; o.w = mt.w + pev.w;
        } else {
            const float4 xv = *(const float4*)(xr + off);
            o.x = xv.x + pev.x; o.y = xv.y + pev.y;
            o.z = xv.z + pev.z; o.w = xv.w + pev.w;
        }
        *(float4*)(xr + off) = o;
    }
}

// ---------------- layernorm ----------------
__global__ __launch_bounds__(256) void ln_kernel(
    const float* __restrict__ x, bf16_t* __restrict__ out,
    const float* __restrict__ s, const float* __restrict__ bvec)
{
    const int wave = threadIdx.x >> 6, lane = threadIdx.x & 63;
    const int row = blockIdx.x * 4 + wave;
    const float* xr = x + (size_t)row * 768;

    float4 v[3];
    float sum = 0.0f, sq = 0.0f;
#pragma unroll
    for (int j = 0; j < 3; ++j) {
        v[j] = *(const float4*)(xr + j * 256 + lane * 4);
        sum += v[j].x + v[j].y + v[j].z + v[j].w;
        sq  += v[j].x * v[j].x + v[j].y * v[j].y + v[j].z * v[j].z + v[j].w * v[j].w;
    }
#pragma unroll
    for (int off = 32; off; off >>= 1) {
        sum += __shfl_xor(sum, off, 64);
        sq  += __shfl_xor(sq, off, 64);
    }
    const float mean = sum * (1.0f / 768.0f);
    const float var = sq * (1.0f / 768.0f) - mean * mean;
    const float inv = rsqrtf(var + 1e-5f);

    bf16_t* orow = out + (size_t)row * 768;
#pragma unroll
    for (int j = 0; j < 3; ++j) {
        const int off = j * 256 + lane * 4;
        const float4 sv = *(const float4*)(s + off);
        const float4 bv = *(const float4*)(bvec + off);
        short4v o;
        o[0] = f2bf_s((v[j].x - mean) * inv * sv.x + bv.x);
        o[1] = f2bf_s((v[j].y - mean) * inv * sv.y + bv.y);
        o[2] = f2bf_s((v[j].z - mean) * inv * sv.z + bv.z);
        o[3] = f2bf_s((v[j].w - mean) * inv * sv.w + bv.w);
        *(short4v*)(orow + off) = o;
    }
}

// ---------------- MFMA flash attention ----------------
__global__ __launch_bounds__(256) void attn_kernel(
    const bf16_t* __restrict__ qkv, bf16_t* __restrict__ out)
{
    const int bh = blockIdx.x;
    const int b = bh / HEADS, h = bh % HEADS;
    const int tid = threadIdx.x, lane = tid & 63, wave = tid >> 6;
    const int quad = lane >> 4, l16 = lane & 15;
    const int wq = wave * 64;

    __shared__ __align__(16) short Vt[64][68];
    __shared__ __align__(16) short Plds[4][64][68];
    __shared__ float red[4][64];

    const size_t tok0 = (size_t)b * NPATCH;
    const int hoff = h * 64;

    bf16x8 qf[4][2];
#pragma unroll
    for (int ni = 0; ni < 4; ++ni) {
        const int q = wq + ni * 16 + l16;
        const int qe = q < 195 ? q : 195;
#pragma unroll
        for (int ks = 0; ks < 2; ++ks)
            qf[ni][ks] = *(const bf16x8*)(qkv + (tok0 + qe) * 2304 + hoff + ks * 32 + quad * 8);
    }

    floatx4 accO[4][4];
#pragma unroll
    for (int i = 0; i < 4; ++i)
#pragma unroll
        for (int j = 0; j < 4; ++j) accO[i][j] = (floatx4)0.0f;
    float mrun[4], lrun[4];
#pragma unroll
    for (int ni = 0; ni < 4; ++ni) { mrun[ni] = -1e30f; lrun[ni] = 0.0f; }

    for (int kc = 0; kc < 256; kc += 64) {
        __syncthreads();
        {
            const int kl = tid & 63;
            const int dg = tid >> 6;
            const int key = kc + kl;
            if (key < NPATCH) {
                const bf16_t* src = qkv + (tok0 + key) * 2304 + 1536 + hoff + dg * 16;
                bf16x8 v0 = *(const bf16x8*)src;
                bf16x8 v1 = *(const bf16x8*)(src + 8);
#pragma unroll
                for (int j = 0; j < 8; ++j) {
                    Vt[dg * 16 + j][kl]     = v0[j];
                    Vt[dg * 16 + 8 + j][kl] = v1[j];
                }
            } else {
#pragma unroll
                for (int j = 0; j < 16; ++j) Vt[dg * 16 + j][kl] = 0;
            }
        }
        __syncthreads();

        bf16x8 af[4][2];
#pragma unroll
        for (int mi = 0; mi < 4; ++mi) {
            const int key = kc + mi * 16 + l16;
            const int ke = key < 195 ? key : 195;
#pragma unroll
            for (int ks = 0; ks < 2; ++ks)
                af[mi][ks] = *(const bf16x8*)(qkv + (tok0 + ke) * 2304 + 768 + hoff + ks * 32 + quad * 8);
        }
        floatx4 accS[4][4];
#pragma unroll
        for (int i = 0; i < 4; ++i)
#pragma unroll
            for (int j = 0; j < 4; ++j) accS[i][j] = (floatx4)0.0f;
#pragma unroll
        for (int mi = 0; mi < 4; ++mi)
#pragma unroll
            for (int ni = 0; ni < 4; ++ni)
#pragma unroll
                for (int ks = 0; ks < 2; ++ks)
                    accS[mi][ni] = __builtin_amdgcn_mfma_f32_16x16x32_bf16(
                        af[mi][ks], qf[ni][ks], accS[mi][ni], 0, 0, 0);

#pragma unroll
        for (int mi = 0; mi < 4; ++mi) {
#pragma unroll
            for (int r = 0; r < 4; ++r) {
                const int key = kc + mi * 16 + quad * 4 + r;
                const bool valid = key < NPATCH;
#pragma unroll
                for (int ni = 0; ni < 4; ++ni)
                    accS[mi][ni][r] = valid ? accS[mi][ni][r] * 0.125f : -1e30f;
            }
        }

        float alpha[4];
#pragma unroll
        for (int ni = 0; ni < 4; ++ni) {
            float mx = -1e30f;
#pragma unroll
            for (int mi = 0; mi < 4; ++mi)
#pragma unroll
                for (int r = 0; r < 4; ++r) mx = fmaxf(mx, accS[mi][ni][r]);
            mx = fmaxf(mx, __shfl_xor(mx, 16, 64));
            mx = fmaxf(mx, __shfl_xor(mx, 32, 64));
            const float mnew = fmaxf(mrun[ni], mx);
            float s = 0.0f;
#pragma unroll
            for (int mi = 0; mi < 4; ++mi)
#pragma unroll
                for (int r = 0; r < 4; ++r) {
                    const float p = __expf(accS[mi][ni][r] - mnew);
                    accS[mi][ni][r] = p;
                    s += p;
                }
            s += __shfl_xor(s, 16, 64);
            s += __shfl_xor(s, 32, 64);
            alpha[ni] = __expf(mrun[ni] - mnew);
            lrun[ni] = lrun[ni] * alpha[ni] + s;
            mrun[ni] = mnew;
        }
        if (quad == 0) {
#pragma unroll
            for (int ni = 0; ni < 4; ++ni) red[wave][ni * 16 + l16] = alpha[ni];
        }

#pragma unroll
        for (int mi = 0; mi < 4; ++mi)
#pragma unroll
            for (int ni = 0; ni < 4; ++ni) {
                short4v pk;
#pragma unroll
                for (int r = 0; r < 4; ++r) pk[r] = f2bf_s(accS[mi][ni][r]);
                *(short4v*)&Plds[wave][ni * 16 + l16][mi * 16 + quad * 4] = pk;
            }
        asm volatile("s_waitcnt lgkmcnt(0)" ::: "memory");

#pragma unroll
        for (int mi = 0; mi < 4; ++mi) {
            const float4 al = *(const float4*)&red[wave][mi * 16 + quad * 4];
#pragma unroll
            for (int ni = 0; ni < 4; ++ni) {
                accO[mi][ni][0] *= al.x;
                accO[mi][ni][1] *= al.y;
                accO[mi][ni][2] *= al.z;
                accO[mi][ni][3] *= al.w;
            }
        }

#pragma unroll
        for (int ks = 0; ks < 2; ++ks) {
            bf16x8 pa[4], vb[4];
#pragma unroll
            for (int mi = 0; mi < 4; ++mi) {
                short4v lo = *(const short4v*)&Plds[wave][mi * 16 + l16][ks * 32 + quad * 8];
                short4v hi = *(const short4v*)&Plds[wave][mi * 16 + l16][ks * 32 + quad * 8 + 4];
                pa[mi] = __builtin_shufflevector(lo, hi, 0, 1, 2, 3, 4, 5, 6, 7);
            }
#pragma unroll
            for (int ni = 0; ni < 4; ++ni) {
                short4v lo = *(const short4v*)&Vt[ni * 16 + l16][ks * 32 + quad * 8];
                short4v hi = *(const short4v*)&Vt[ni * 16 + l16][ks * 32 + quad * 8 + 4];
                vb[ni] = __builtin_shufflevector(lo, hi, 0, 1, 2, 3, 4, 5, 6, 7);
            }
#pragma unroll
            for (int mi = 0; mi < 4; ++mi)
#pragma unroll
                for (int ni = 0; ni < 4; ++ni)
                    accO[mi][ni] = __builtin_amdgcn_mfma_f32_16x16x32_bf16(
                        pa[mi], vb[ni], accO[mi][ni], 0, 0, 0);
        }
    }

    if (quad == 0) {
#pragma unroll
        for (int ni = 0; ni < 4; ++ni) red[wave][ni * 16 + l16] = lrun[ni];
    }
    asm volatile("s_waitcnt lgkmcnt(0)" ::: "memory");
#pragma unroll
    for (int mi = 0; mi < 4; ++mi) {
        const float4 lv = *(const float4*)&red[wave][mi * 16 + quad * 4];
        const float inv[4] = {1.0f / lv.x, 1.0f / lv.y, 1.0f / lv.z, 1.0f / lv.w};
#pragma unroll
        for (int r = 0; r < 4; ++r) {
            const int q = wq + mi * 16 + quad * 4 + r;
            if (q < NPATCH) {
#pragma unroll
                for (int ni = 0; ni < 4; ++ni) {
                    const int d = ni * 16 + l16;
                    out[(tok0 + q) * 768 + hoff + d] =
                        __float2bfloat16(accO[mi][ni][r] * inv[r]);
                }
            }
        }
    }
}

// ---------------- gather masked rows ----------------
__global__ __launch_bounds__(256) void gather_kernel(
    const float* __restrict__ x, const int* __restrict__ midx, bf16_t* __restrict__ em)
{
    const int row = blockIdx.x;
    const int b = row / NMASK;
    const int n = midx[row];
    const float* src = x + (size_t)(b * NPATCH + n) * 768;
    bf16_t* dst = em + (size_t)row * 768;
    for (int e = threadIdx.x; e < 768; e += 256) dst[e] = __float2bfloat16(src[e]);
}

__global__ void zero_kernel(float* __restrict__ p) {
    if (threadIdx.x == 0 && blockIdx.x == 0) p[0] = 0.0f;
}

// ---------------- L1 loss ----------------
__global__ __launch_bounds__(256) void loss_kernel(
    const float* __restrict__ pred, const float* __restrict__ img,
    const int* __restrict__ midx, float* __restrict__ acc)
{
    const size_t total = (size_t)MROWS * 768;
    float part = 0.0f;
    for (size_t idx = (size_t)blockIdx.x * blockDim.x + threadIdx.x; idx < total;
         idx += (size_t)gridDim.x * blockDim.x) {
        const int e = (int)(idx % 768);
        const int row = (int)(idx / 768);
        const int b = row / NMASK;
        const int n = midx[row];
        const int c = e % 3, pix = e / 3;
        const int py = pix / 16, px = pix % 16;
        const int gy = n / 14, gx = n % 14;
        const float ref =
            img[(((size_t)b * 224 + gy * 16 + py) * 224 + gx * 16 + px) * 3 + c];
        part += fabsf(pred[idx] - ref);
    }
#pragma unroll
    for (int off = 32; off; off >>= 1) part += __shfl_down(part, off, 64);
    __shared__ float sp[4];
    if ((threadIdx.x & 63) == 0) sp[threadIdx.x >> 6] = part;
    __syncthreads();
    if (threadIdx.x == 0) atomicAdd(acc, sp[0] + sp[1] + sp[2] + sp[3]);
}

__global__ void finalize_kernel(const float* __restrict__ acc, float* __restrict__ out)
{
    if (threadIdx.x == 0 && blockIdx.x == 0)
        out[0] = acc[0] * (float)(1.0 / 472055808.0);   // 1/(64*98*768*98)
}

// ---------------- launch ----------------
extern "C" void kernel_launch(void* const* d_in, const int* in_sizes, int n_in,
                              void* d_out, int out_size, void* d_ws, size_t ws_size,
                              hipStream_t stream)
{
    const float* img      = (const float*)d_in[0];
    const float* noise    = (const float*)d_in[1];
    const float* patch_w  = (const float*)d_in[2];
    const float* patch_b  = (const float*)d_in[3];
    const float* pos_emb  = (const float*)d_in[4];
    const float* mask_tok = (const float*)d_in[5];
    const float* ln1_s    = (const float*)d_in[6];
    const float* ln1_b    = (const float*)d_in[7];
    const float* wqkv     = (const float*)d_in[8];
    const float* bqkv     = (const float*)d_in[9];
    const float* wo       = (const float*)d_in[10];
    const float* bo       = (const float*)d_in[11];
    const float* ln2_s    = (const float*)d_in[12];
    const float* ln2_b    = (const float*)d_in[13];
    const float* w1       = (const float*)d_in[14];
    const float* b1       = (const float*)d_in[15];
    const float* w2       = (const float*)d_in[16];
    const float* b2       = (const float*)d_in[17];
    const float* pix_w    = (const float*)d_in[18];
    const float* pix_b    = (const float*)d_in[19];

    const size_t TOK = (size_t)TOKENS * 768;
    float*  x    = (float*)d_ws;
    bf16_t* h    = (bf16_t*)(x + TOK);
    bf16_t* qbuf = h + TOK;
    bf16_t* wts  = qbuf + (size_t)TOKENS * 2304;
    size_t o = 0;
    bf16_t* patch_wT = wts + o; o += (size_t)768 * 768;
    bf16_t* wqkvT    = wts + o; o += (size_t)DEPTH * 2304 * 768;
    bf16_t* woT      = wts + o; o += (size_t)DEPTH * 768 * 768;
    bf16_t* w1T      = wts + o; o += (size_t)DEPTH * 3072 * 768;
    bf16_t* w2T      = wts + o; o += (size_t)DEPTH * 768 * 3072;
    bf16_t* pix_wT   = wts + o; o += (size_t)768 * 768;
    int* flags = (int*)(wts + o);
    int* midx  = flags + TOKENS;
    float* acc = (float*)(midx + MROWS);

    // optional full-M MLP intermediate (77 MB) if the workspace has room
    size_t used = (size_t)((char*)(acc + 1) - (char*)d_ws);
    used = (used + 255) & ~(size_t)255;
    bf16_t* mlpbuf = (bf16_t*)((char*)d_ws + used);
    const bool fullmlp =
        ws_size >= used + (size_t)TOKENS * MLPDIM * sizeof(bf16_t);

    bf16_t* patches = qbuf;
    float*  pred    = (float*)qbuf;

    wconvT<<<dim3(768/32, 768/32, 1), 256, 0, stream>>>(patch_w, patch_wT, 768, 768);
    wconvT<<<dim3(2304/32, 768/32, DEPTH), 256, 0, stream>>>(wqkv, wqkvT, 768, 2304);
    wconvT<<<dim3(768/32, 768/32, DEPTH), 256, 0, stream>>>(wo, woT, 768, 768);
    wconvT<<<dim3(3072/32, 768/32, DEPTH), 256, 0, stream>>>(w1, w1T, 768, 3072);
    wconvT<<<dim3(768/32, 3072/32, DEPTH), 256, 0, stream>>>(w2, w2T, 3072, 768);
    wconvT<<<dim3(768/32, 768/32, 1), 256, 0, stream>>>(pix_w, pix_wT, 768, 768);

    patchify_kernel<<<TOKENS, 256, 0, stream>>>(img, patches);
    mask_kernel<<<BATCH, 256, 0, stream>>>(noise, flags, midx);

    mm_bf16<0><<<dim3(768/128, TOKENS/128), 256, 0, stream>>>(
        patches, patch_wT, patch_b, nullptr, x, TOKENS, 768, 768);
    pe_mask_kernel<<<TOKENS/4, 256, 0, stream>>>(x, pos_emb, mask_tok, flags);

    for (int l = 0; l < DEPTH; ++l) {
        ln_kernel<<<TOKENS/4, 256, 0, stream>>>(x, h, ln1_s + l * 768, ln1_b + l * 768);
        mm_bf16<3><<<dim3(2304/128, TOKENS/128), 256, 0, stream>>>(
            h, wqkvT + (size_t)l * 2304 * 768, bqkv + l * 2304, nullptr, qbuf,
            TOKENS, 2304, 768);
        attn_kernel<<<BATCH * HEADS, 256, 0, stream>>>(qbuf, h);
        mm_bf16<2><<<dim3(768/128, TOKENS/128), 256, 0, stream>>>(
            h, woT + (size_t)l * 768 * 768, bo + l * 768, x, x, TOKENS, 768, 768);
        ln_kernel<<<TOKENS/4, 256, 0, stream>>>(x, h, ln2_s + l * 768, ln2_b + l * 768);
        if (fullmlp) {
            mm_bf16<1><<<dim3(MLPDIM/128, TOKENS/128), 256, 0, stream>>>(
                h, w1T + (size_t)l * 3072 * 768, b1 + l * MLPDIM, nullptr, mlpbuf,
                TOKENS, MLPDIM, 768);
            mm_bf16<2><<<dim3(768/128, TOKENS/128), 256, 0, stream>>>(
                mlpbuf, w2T + (size_t)l * 768 * 3072, b2 + l * 768, x, x,
                TOKENS, 768, MLPDIM);
        } else {
            for (int ch = 0; ch < 2; ++ch) {
                bf16_t* hA = h + (size_t)ch * HALFROWS * 768;
                float*  xC = x + (size_t)ch * HALFROWS * 768;
                mm_bf16<1><<<dim3(MLPDIM/128, HALFROWS/128), 256, 0, stream>>>(
                    hA, w1T + (size_t)l * 3072 * 768, b1 + l * MLPDIM, nullptr, qbuf,
                    HALFROWS, MLPDIM, 768);
                mm_bf16<2><<<dim3(768/128, HALFROWS/128), 256, 0, stream>>>(
                    qbuf, w2T + (size_t)l * 768 * 3072, b2 + l * 768, xC, xC,
                    HALFROWS, 768, MLPDIM);
            }
        }
    }

    gather_kernel<<<MROWS, 256, 0, stream>>>(x, midx, h);
    mm_bf16<0><<<dim3(768/128, MROWS/128), 256, 0, stream>>>(
        h, pix_wT, pix_b, nullptr, pred, MROWS, 768, 768);

    zero_kernel<<<1, 64, 0, stream>>>(acc);
    loss_kernel<<<4704, 256, 0, stream>>>(pred, img, midx, acc);
    finalize_kernel<<<1, 64, 0, stream>>>(acc, (float*)d_out);
}

// Round 4
// 2556.121 us; speedup vs baseline: 1.1699x; 1.1502x over previous
//
#include <hip/hip_runtime.h>
#include <hip/hip_bf16.h>
#include <math.h>

// ---------------- problem constants ----------------
#define BATCH   64
#define NPATCH  196
#define DIM     768
#define DEPTH   6
#define HEADS   12
#define DHEAD   64
#define MLPDIM  3072
#define NMASK   98
#define TOKENS  (BATCH*NPATCH)      // 12544
#define MROWS   (BATCH*NMASK)       // 6272
#define HALFROWS (TOKENS/2)         // 6272

using bf16_t = __hip_bfloat16;
typedef short bf16x8 __attribute__((ext_vector_type(8)));
typedef short short4v __attribute__((ext_vector_type(4)));
typedef float floatx4 __attribute__((ext_vector_type(4)));

__device__ inline float gelu_f(float v) {
    const float c = 0.7978845608028654f;
    float t = tanhf(c * (v + 0.044715f * v * v * v));
    return 0.5f * v * (1.0f + t);
}

__device__ __forceinline__ short f2bf_s(float f) {
    bf16_t t = __float2bfloat16(f);
    return *reinterpret_cast<short*>(&t);
}

__device__ __forceinline__ void gload_lds16(const bf16_t* g, bf16_t* l) {
    __builtin_amdgcn_global_load_lds(
        (const __attribute__((address_space(1))) unsigned int*)g,
        (__attribute__((address_space(3))) unsigned int*)l, 16, 0, 0);
}

// bijective XCD-chunked swizzle (m204): contiguous wg ranges per XCD.
__device__ __forceinline__ int xcd_swz(int orig, int nwg) {
    const int qq = nwg >> 3, rr = nwg & 7;
    const int xcd = orig & 7, seq = orig >> 3;
    return (xcd < rr ? xcd * (qq + 1) : rr * (qq + 1) + (xcd - rr) * qq) + seq;
}

// ---------------- 128x128 bf16 MFMA GEMM: C = A(MxK) @ BT(NxK)^T + bias ------
// MODE 0: bias -> fp32   MODE 1: bias+gelu -> bf16   MODE 2: bias+residual -> fp32
// MODE 3: bias -> bf16
// Single-buffered BK=64, 32 KB LDS -> 4 blocks/CU. Used for LARGE grids
// (qkv: 1764 blocks, w1: 1176/dispatch) where TLP is already sufficient.
// LDS K-chunk XOR swizzle: slot p of row r holds chunk p ^ (r&7).
template<int MODE>
__global__ __launch_bounds__(256) void mm_bf16(
    const bf16_t* __restrict__ A, const bf16_t* __restrict__ BT,
    const float* __restrict__ bias, const float* __restrict__ Cin,
    void* __restrict__ Cout, int M, int N, int K)
{
    __shared__ __align__(16) bf16_t As[128 * 64];
    __shared__ __align__(16) bf16_t Bs[128 * 64];

    const int tid  = threadIdx.x;
    const int lane = tid & 63;
    const int wave = tid >> 6;
    const int wm = (wave >> 1) * 64;
    const int wn = (wave & 1) * 64;

    const int gx  = gridDim.x;
    const int wg = xcd_swz(blockIdx.y * gx + blockIdx.x, gx * gridDim.y);
    const int m0 = (wg / gx) * 128;
    const int n0 = (wg % gx) * 128;

    const int srow = tid >> 3;
    const int schunk = (tid & 7) ^ (srow & 7);
    const bf16_t* gA = A  + (size_t)(m0 + srow) * K + schunk * 8;
    const bf16_t* gB = BT + (size_t)(n0 + srow) * K + schunk * 8;
    bf16_t* lA = &As[tid * 8];
    bf16_t* lB = &Bs[tid * 8];

    floatx4 acc[4][4];
#pragma unroll
    for (int i = 0; i < 4; ++i)
#pragma unroll
        for (int j = 0; j < 4; ++j) acc[i][j] = (floatx4)0.0f;

    const int quad = lane >> 4;
    const int rm = lane & 15;

    for (int k0 = 0; k0 < K; k0 += 64) {
        __syncthreads();
#pragma unroll
        for (int i = 0; i < 4; ++i) {
            gload_lds16(gA + k0 + (size_t)(32 * i) * K, lA + i * 2048);
            gload_lds16(gB + k0 + (size_t)(32 * i) * K, lB + i * 2048);
        }
        __syncthreads();

#pragma unroll
        for (int kk = 0; kk < 2; ++kk) {
            const int kq = (((kk << 2) | quad) ^ (rm & 7)) * 8;
            bf16x8 a[4], b[4];
#pragma unroll
            for (int mi = 0; mi < 4; ++mi)
                a[mi] = *(const bf16x8*)&As[(wm + mi * 16 + rm) * 64 + kq];
#pragma unroll
            for (int ni = 0; ni < 4; ++ni)
                b[ni] = *(const bf16x8*)&Bs[(wn + ni * 16 + rm) * 64 + kq];
#pragma unroll
            for (int mi = 0; mi < 4; ++mi)
#pragma unroll
                for (int ni = 0; ni < 4; ++ni)
                    acc[mi][ni] = __builtin_amdgcn_mfma_f32_16x16x32_bf16(
                        a[mi], b[ni], acc[mi][ni], 0, 0, 0);
        }
    }

    const int cm = m0 + wm + quad * 4;
    const int cn = n0 + wn + rm;
#pragma unroll
    for (int mi = 0; mi < 4; ++mi) {
#pragma unroll
        for (int ni = 0; ni < 4; ++ni) {
#pragma unroll
            for (int r = 0; r < 4; ++r) {
                const int row = cm + mi * 16 + r;
                const int col = cn + ni * 16;
                float v = acc[mi][ni][r] + bias[col];
                const size_t idx = (size_t)row * N + col;
                if (MODE == 0) {
                    ((float*)Cout)[idx] = v;
                } else if (MODE == 1) {
                    ((bf16_t*)Cout)[idx] = __float2bfloat16(gelu_f(v));
                } else if (MODE == 2) {
                    ((float*)Cout)[idx] = v + Cin[idx];
                } else {
                    ((bf16_t*)Cout)[idx] = __float2bfloat16(v);
                }
            }
        }
    }
}

// ---------------- 64x64 bf16 MFMA GEMM (small-N variant) ----------------
// For the N=768 GEMM family (wo, w2, patch-embed, pix): a 128x128 grid is
// only 294-588 blocks -> ~1 block/CU -> per-CU staging throughput bound
// (round-3 counters: 76us, Occ 11%, HBM 11%, MfmaUtil 14%). 64x64 tiles
// quadruple the grid (1176-2352 blocks) and cut LDS to 16 KB -> ~5-6
// blocks/CU resident, so one block's staging drain overlaps others'
// compute. Extra A re-reads (N/64 passes) are absorbed by L2/L3 via the
// XCD swizzle (12 consecutive n-blocks per chunk share one A panel).
template<int MODE>
__global__ __launch_bounds__(256) void mm64_bf16(
    const bf16_t* __restrict__ A, const bf16_t* __restrict__ BT,
    const float* __restrict__ bias, const float* __restrict__ Cin,
    void* __restrict__ Cout, int M, int N, int K)
{
    __shared__ __align__(16) bf16_t As[64 * 64];
    __shared__ __align__(16) bf16_t Bs[64 * 64];

    const int tid  = threadIdx.x;
    const int lane = tid & 63;
    const int wave = tid >> 6;
    const int wm = (wave >> 1) * 32;
    const int wn = (wave & 1) * 32;

    const int gx  = gridDim.x;
    const int wg = xcd_swz(blockIdx.y * gx + blockIdx.x, gx * gridDim.y);
    const int m0 = (wg / gx) * 64;
    const int n0 = (wg % gx) * 64;

    // staging: 256 threads x 16B = 4 KB/round = 32 rows x 64 cols; 2 rounds
    // per matrix. slot p of row r holds chunk p ^ (r&7) (r&7 invariant
    // under +32).
    const int srow = tid >> 3;                 // 0..31
    const int schunk = (tid & 7) ^ (srow & 7);
    const bf16_t* gA = A  + (size_t)(m0 + srow) * K + schunk * 8;
    const bf16_t* gB = BT + (size_t)(n0 + srow) * K + schunk * 8;
    bf16_t* lA = &As[tid * 8];
    bf16_t* lB = &Bs[tid * 8];

    floatx4 acc[2][2];
#pragma unroll
    for (int i = 0; i < 2; ++i)
#pragma unroll
        for (int j = 0; j < 2; ++j) acc[i][j] = (floatx4)0.0f;

    const int quad = lane >> 4;
    const int rm = lane & 15;

    for (int k0 = 0; k0 < K; k0 += 64) {
        __syncthreads();
#pragma unroll
        for (int i = 0; i < 2; ++i) {
            gload_lds16(gA + k0 + (size_t)(32 * i) * K, lA + i * 2048);
            gload_lds16(gB + k0 + (size_t)(32 * i) * K, lB + i * 2048);
        }
        __syncthreads();

#pragma unroll
        for (int kk = 0; kk < 2; ++kk) {
            const int kq = (((kk << 2) | quad) ^ (rm & 7)) * 8;
            bf16x8 a[2], b[2];
#pragma unroll
            for (int mi = 0; mi < 2; ++mi)
                a[mi] = *(const bf16x8*)&As[(wm + mi * 16 + rm) * 64 + kq];
#pragma unroll
            for (int ni = 0; ni < 2; ++ni)
                b[ni] = *(const bf16x8*)&Bs[(wn + ni * 16 + rm) * 64 + kq];
#pragma unroll
            for (int mi = 0; mi < 2; ++mi)
#pragma unroll
                for (int ni = 0; ni < 2; ++ni)
                    acc[mi][ni] = __builtin_amdgcn_mfma_f32_16x16x32_bf16(
                        a[mi], b[ni], acc[mi][ni], 0, 0, 0);
        }
    }

    const int cm = m0 + wm + quad * 4;
    const int cn = n0 + wn + rm;
#pragma unroll
    for (int mi = 0; mi < 2; ++mi) {
#pragma unroll
        for (int ni = 0; ni < 2; ++ni) {
#pragma unroll
            for (int r = 0; r < 4; ++r) {
                const int row = cm + mi * 16 + r;
                const int col = cn + ni * 16;
                float v = acc[mi][ni][r] + bias[col];
                const size_t idx = (size_t)row * N + col;
                if (MODE == 0) {
                    ((float*)Cout)[idx] = v;
                } else if (MODE == 1) {
                    ((bf16_t*)Cout)[idx] = __float2bfloat16(gelu_f(v));
                } else if (MODE == 2) {
                    ((float*)Cout)[idx] = v + Cin[idx];
                } else {
                    ((bf16_t*)Cout)[idx] = __float2bfloat16(v);
                }
            }
        }
    }
}

// ---------------- weight convert + transpose ----------------
__global__ __launch_bounds__(256) void wconvT(
    const float* __restrict__ W, bf16_t* __restrict__ WT, int K, int N)
{
    __shared__ float t[32][33];
    const size_t off = (size_t)blockIdx.z * K * N;
    const int k0 = blockIdx.y * 32, n0 = blockIdx.x * 32;
    const int r = threadIdx.x >> 5, c = threadIdx.x & 31;
#pragma unroll
    for (int i = 0; i < 4; ++i)
        t[r + i * 8][c] = W[off + (size_t)(k0 + r + i * 8) * N + n0 + c];
    __syncthreads();
#pragma unroll
    for (int i = 0; i < 4; ++i)
        WT[off + (size_t)(n0 + r + i * 8) * K + k0 + c] =
            __float2bfloat16(t[c][r + i * 8]);
}

// ---------------- patchify ----------------
__global__ __launch_bounds__(256) void patchify_kernel(
    const float* __restrict__ img, bf16_t* __restrict__ patches)
{
    const int row = blockIdx.x;
    const int b = row / NPATCH, p = row % NPATCH;
    const int gy = p / 14, gx = p % 14;
    for (int e = threadIdx.x; e < 768; e += 256) {
        const int c = e % 3, pix = e / 3;
        const int py = pix / 16, px = pix % 16;
        const size_t src = (((size_t)b * 224 + gy * 16 + py) * 224 + gx * 16 + px) * 3 + c;
        patches[(size_t)row * 768 + e] = __float2bfloat16(img[src]);
    }
}

// ---------------- mask top-k ----------------
__global__ __launch_bounds__(256) void mask_kernel(
    const float* __restrict__ noise, int* __restrict__ flags, int* __restrict__ midx)
{
    const int b = blockIdx.x;
    __shared__ float v[NPATCH];
    const int t = threadIdx.x;
    if (t < NPATCH) v[t] = noise[b * NPATCH + t];
    __syncthreads();
    if (t < NPATCH) {
        const float mine = v[t];
        int r = 0;
        for (int j = 0; j < NPATCH; ++j) {
            const float o = v[j];
            r += (o > mine) || (o == mine && j < t);
        }
        const int f = (r < NMASK) ? 1 : 0;
        flags[b * NPATCH + t] = f;
        if (f) midx[b * NMASK + r] = t;
    }
}

// ---------------- pos-emb add + mask-token substitute ----------------
__global__ __launch_bounds__(256) void pe_mask_kernel(
    float* __restrict__ x, const float* __restrict__ pos_emb,
    const float* __restrict__ mask_token, const int* __restrict__ flags)
{
    const int wave = threadIdx.x >> 6, lane = threadIdx.x & 63;
    const int row = blockIdx.x * 4 + wave;
    const int n = row % NPATCH;
    const int masked = flags[row];
    const float* pe = pos_emb + (size_t)(n + 1) * 768;
    float* xr = x + (size_t)row * 768;
#pragma unroll
    for (int j = 0; j < 3; ++j) {
        const int off = j * 256 + lane * 4;
        const float4 pev = *(const float4*)(pe + off);
        float4 o;
        if (masked) {
            const float4 mt = *(const float4*)(mask_token + off);
            o.x = mt.x + pev.x; o.y = mt.y + pev.y;
            o.z = mt.z + pev.z; o.w = mt.w + pev.w;
        } else {
            const float4 xv = *(const float4*)(xr + off);
            o.x = xv.x + pev.x; o.y = xv.y + pev.y;
            o.z = xv.z + pev.z; o.w = xv.w + pev.w;
        }
        *(float4*)(xr + off) = o;
    }
}

// ---------------- layernorm ----------------
__global__ __launch_bounds__(256) void ln_kernel(
    const float* __restrict__ x, bf16_t* __restrict__ out,
    const float* __restrict__ s, const float* __restrict__ bvec)
{
    const int wave = threadIdx.x >> 6, lane = threadIdx.x & 63;
    const int row = blockIdx.x * 4 + wave;
    const float* xr = x + (size_t)row * 768;

    float4 v[3];
    float sum = 0.0f, sq = 0.0f;
#pragma unroll
    for (int j = 0; j < 3; ++j) {
        v[j] = *(const float4*)(xr + j * 256 + lane * 4);
        sum += v[j].x + v[j].y + v[j].z + v[j].w;
        sq  += v[j].x * v[j].x + v[j].y * v[j].y + v[j].z * v[j].z + v[j].w * v[j].w;
    }
#pragma unroll
    for (int off = 32; off; off >>= 1) {
        sum += __shfl_xor(sum, off, 64);
        sq  += __shfl_xor(sq, off, 64);
    }
    const float mean = sum * (1.0f / 768.0f);
    const float var = sq * (1.0f / 768.0f) - mean * mean;
    const float inv = rsqrtf(var + 1e-5f);

    bf16_t* orow = out + (size_t)row * 768;
#pragma unroll
    for (int j = 0; j < 3; ++j) {
        const int off = j * 256 + lane * 4;
        const float4 sv = *(const float4*)(s + off);
        const float4 bv = *(const float4*)(bvec + off);
        short4v o;
        o[0] = f2bf_s((v[j].x - mean) * inv * sv.x + bv.x);
        o[1] = f2bf_s((v[j].y - mean) * inv * sv.y + bv.y);
        o[2] = f2bf_s((v[j].z - mean) * inv * sv.z + bv.z);
        o[3] = f2bf_s((v[j].w - mean) * inv * sv.w + bv.w);
        *(short4v*)(orow + off) = o;
    }
}

// ---------------- MFMA flash attention ----------------
__global__ __launch_bounds__(256) void attn_kernel(
    const bf16_t* __restrict__ qkv, bf16_t* __restrict__ out)
{
    const int bh = blockIdx.x;
    const int b = bh / HEADS, h = bh % HEADS;
    const int tid = threadIdx.x, lane = tid & 63, wave = tid >> 6;
    const int quad = lane >> 4, l16 = lane & 15;
    const int wq = wave * 64;

    __shared__ __align__(16) short Vt[64][68];
    __shared__ __align__(16) short Plds[4][64][68];
    __shared__ float red[4][64];

    const size_t tok0 = (size_t)b * NPATCH;
    const int hoff = h * 64;

    bf16x8 qf[4][2];
#pragma unroll
    for (int ni = 0; ni < 4; ++ni) {
        const int q = wq + ni * 16 + l16;
        const int qe = q < 195 ? q : 195;
#pragma unroll
        for (int ks = 0; ks < 2; ++ks)
            qf[ni][ks] = *(const bf16x8*)(qkv + (tok0 + qe) * 2304 + hoff + ks * 32 + quad * 8);
    }

    floatx4 accO[4][4];
#pragma unroll
    for (int i = 0; i < 4; ++i)
#pragma unroll
        for (int j = 0; j < 4; ++j) accO[i][j] = (floatx4)0.0f;
    float mrun[4], lrun[4];
#pragma unroll
    for (int ni = 0; ni < 4; ++ni) { mrun[ni] = -1e30f; lrun[ni] = 0.0f; }

    for (int kc = 0; kc < 256; kc += 64) {
        __syncthreads();
        {
            const int kl = tid & 63;
            const int dg = tid >> 6;
            const int key = kc + kl;
            if (key < NPATCH) {
                const bf16_t* src = qkv + (tok0 + key) * 2304 + 1536 + hoff + dg * 16;
                bf16x8 v0 = *(const bf16x8*)src;
                bf16x8 v1 = *(const bf16x8*)(src + 8);
#pragma unroll
                for (int j = 0; j < 8; ++j) {
                    Vt[dg * 16 + j][kl]     = v0[j];
                    Vt[dg * 16 + 8 + j][kl] = v1[j];
                }
            } else {
#pragma unroll
                for (int j = 0; j < 16; ++j) Vt[dg * 16 + j][kl] = 0;
            }
        }
        __syncthreads();

        bf16x8 af[4][2];
#pragma unroll
        for (int mi = 0; mi < 4; ++mi) {
            const int key = kc + mi * 16 + l16;
            const int ke = key < 195 ? key : 195;
#pragma unroll
            for (int ks = 0; ks < 2; ++ks)
                af[mi][ks] = *(const bf16x8*)(qkv + (tok0 + ke) * 2304 + 768 + hoff + ks * 32 + quad * 8);
        }
        floatx4 accS[4][4];
#pragma unroll
        for (int i = 0; i < 4; ++i)
#pragma unroll
            for (int j = 0; j < 4; ++j) accS[i][j] = (floatx4)0.0f;
#pragma unroll
        for (int mi = 0; mi < 4; ++mi)
#pragma unroll
            for (int ni = 0; ni < 4; ++ni)
#pragma unroll
                for (int ks = 0; ks < 2; ++ks)
                    accS[mi][ni] = __builtin_amdgcn_mfma_f32_16x16x32_bf16(
                        af[mi][ks], qf[ni][ks], accS[mi][ni], 0, 0, 0);

#pragma unroll
        for (int mi = 0; mi < 4; ++mi) {
#pragma unroll
            for (int r = 0; r < 4; ++r) {
                const int key = kc + mi * 16 + quad * 4 + r;
                const bool valid = key < NPATCH;
#pragma unroll
                for (int ni = 0; ni < 4; ++ni)
                    accS[mi][ni][r] = valid ? accS[mi][ni][r] * 0.125f : -1e30f;
            }
        }

        float alpha[4];
#pragma unroll
        for (int ni = 0; ni < 4; ++ni) {
            float mx = -1e30f;
#pragma unroll
            for (int mi = 0; mi < 4; ++mi)
#pragma unroll
                for (int r = 0; r < 4; ++r) mx = fmaxf(mx, accS[mi][ni][r]);
            mx = fmaxf(mx, __shfl_xor(mx, 16, 64));
            mx = fmaxf(mx, __shfl_xor(mx, 32, 64));
            const float mnew = fmaxf(mrun[ni], mx);
            float s = 0.0f;
#pragma unroll
            for (int mi = 0; mi < 4; ++mi)
#pragma unroll
                for (int r = 0; r < 4; ++r) {
                    const float p = __expf(accS[mi][ni][r] - mnew);
                    accS[mi][ni][r] = p;
                    s += p;
                }
            s += __shfl_xor(s, 16, 64);
            s += __shfl_xor(s, 32, 64);
            alpha[ni] = __expf(mrun[ni] - mnew);
            lrun[ni] = lrun[ni] * alpha[ni] + s;
            mrun[ni] = mnew;
        }
        if (quad == 0) {
#pragma unroll
            for (int ni = 0; ni < 4; ++ni) red[wave][ni * 16 + l16] = alpha[ni];
        }

#pragma unroll
        for (int mi = 0; mi < 4; ++mi)
#pragma unroll
            for (int ni = 0; ni < 4; ++ni) {
                short4v pk;
#pragma unroll
                for (int r = 0; r < 4; ++r) pk[r] = f2bf_s(accS[mi][ni][r]);
                *(short4v*)&Plds[wave][ni * 16 + l16][mi * 16 + quad * 4] = pk;
            }
        asm volatile("s_waitcnt lgkmcnt(0)" ::: "memory");

#pragma unroll
        for (int mi = 0; mi < 4; ++mi) {
            const float4 al = *(const float4*)&red[wave][mi * 16 + quad * 4];
#pragma unroll
            for (int ni = 0; ni < 4; ++ni) {
                accO[mi][ni][0] *= al.x;
                accO[mi][ni][1] *= al.y;
                accO[mi][ni][2] *= al.z;
                accO[mi][ni][3] *= al.w;
            }
        }

#pragma unroll
        for (int ks = 0; ks < 2; ++ks) {
            bf16x8 pa[4], vb[4];
#pragma unroll
            for (int mi = 0; mi < 4; ++mi) {
                short4v lo = *(const short4v*)&Plds[wave][mi * 16 + l16][ks * 32 + quad * 8];
                short4v hi = *(const short4v*)&Plds[wave][mi * 16 + l16][ks * 32 + quad * 8 + 4];
                pa[mi] = __builtin_shufflevector(lo, hi, 0, 1, 2, 3, 4, 5, 6, 7);
            }
#pragma unroll
            for (int ni = 0; ni < 4; ++ni) {
                short4v lo = *(const short4v*)&Vt[ni * 16 + l16][ks * 32 + quad * 8];
                short4v hi = *(const short4v*)&Vt[ni * 16 + l16][ks * 32 + quad * 8 + 4];
                vb[ni] = __builtin_shufflevector(lo, hi, 0, 1, 2, 3, 4, 5, 6, 7);
            }
#pragma unroll
            for (int mi = 0; mi < 4; ++mi)
#pragma unroll
                for (int ni = 0; ni < 4; ++ni)
                    accO[mi][ni] = __builtin_amdgcn_mfma_f32_16x16x32_bf16(
                        pa[mi], vb[ni], accO[mi][ni], 0, 0, 0);
        }
    }

    if (quad == 0) {
#pragma unroll
        for (int ni = 0; ni < 4; ++ni) red[wave][ni * 16 + l16] = lrun[ni];
    }
    asm volatile("s_waitcnt lgkmcnt(0)" ::: "memory");
#pragma unroll
    for (int mi = 0; mi < 4; ++mi) {
        const float4 lv = *(const float4*)&red[wave][mi * 16 + quad * 4];
        const float inv[4] = {1.0f / lv.x, 1.0f / lv.y, 1.0f / lv.z, 1.0f / lv.w};
#pragma unroll
        for (int r = 0; r < 4; ++r) {
            const int q = wq + mi * 16 + quad * 4 + r;
            if (q < NPATCH) {
#pragma unroll
                for (int ni = 0; ni < 4; ++ni) {
                    const int d = ni * 16 + l16;
                    out[(tok0 + q) * 768 + hoff + d] =
                        __float2bfloat16(accO[mi][ni][r] * inv[r]);
                }
            }
        }
    }
}

// ---------------- gather masked rows ----------------
__global__ __launch_bounds__(256) void gather_kernel(
    const float* __restrict__ x, const int* __restrict__ midx, bf16_t* __restrict__ em)
{
    const int row = blockIdx.x;
    const int b = row / NMASK;
    const int n = midx[row];
    const float* src = x + (size_t)(b * NPATCH + n) * 768;
    bf16_t* dst = em + (size_t)row * 768;
    for (int e = threadIdx.x; e < 768; e += 256) dst[e] = __float2bfloat16(src[e]);
}

__global__ void zero_kernel(float* __restrict__ p) {
    if (threadIdx.x == 0 && blockIdx.x == 0) p[0] = 0.0f;
}

// ---------------- L1 loss ----------------
__global__ __launch_bounds__(256) void loss_kernel(
    const float* __restrict__ pred, const float* __restrict__ img,
    const int* __restrict__ midx, float* __restrict__ acc)
{
    const size_t total = (size_t)MROWS * 768;
    float part = 0.0f;
    for (size_t idx = (size_t)blockIdx.x * blockDim.x + threadIdx.x; idx < total;
         idx += (size_t)gridDim.x * blockDim.x) {
        const int e = (int)(idx % 768);
        const int row = (int)(idx / 768);
        const int b = row / NMASK;
        const int n = midx[row];
        const int c = e % 3, pix = e / 3;
        const int py = pix / 16, px = pix % 16;
        const int gy = n / 14, gx = n % 14;
        const float ref =
            img[(((size_t)b * 224 + gy * 16 + py) * 224 + gx * 16 + px) * 3 + c];
        part += fabsf(pred[idx] - ref);
    }
#pragma unroll
    for (int off = 32; off; off >>= 1) part += __shfl_down(part, off, 64);
    __shared__ float sp[4];
    if ((threadIdx.x & 63) == 0) sp[threadIdx.x >> 6] = part;
    __syncthreads();
    if (threadIdx.x == 0) atomicAdd(acc, sp[0] + sp[1] + sp[2] + sp[3]);
}

__global__ void finalize_kernel(const float* __restrict__ acc, float* __restrict__ out)
{
    if (threadIdx.x == 0 && blockIdx.x == 0)
        out[0] = acc[0] * (float)(1.0 / 472055808.0);   // 1/(64*98*768*98)
}

// ---------------- launch ----------------
extern "C" void kernel_launch(void* const* d_in, const int* in_sizes, int n_in,
                              void* d_out, int out_size, void* d_ws, size_t ws_size,
                              hipStream_t stream)
{
    const float* img      = (const float*)d_in[0];
    const float* noise    = (const float*)d_in[1];
    const float* patch_w  = (const float*)d_in[2];
    const float* patch_b  = (const float*)d_in[3];
    const float* pos_emb  = (const float*)d_in[4];
    const float* mask_tok = (const float*)d_in[5];
    const float* ln1_s    = (const float*)d_in[6];
    const float* ln1_b    = (const float*)d_in[7];
    const float* wqkv     = (const float*)d_in[8];
    const float* bqkv     = (const float*)d_in[9];
    const float* wo       = (const float*)d_in[10];
    const float* bo       = (const float*)d_in[11];
    const float* ln2_s    = (const float*)d_in[12];
    const float* ln2_b    = (const float*)d_in[13];
    const float* w1       = (const float*)d_in[14];
    const float* b1       = (const float*)d_in[15];
    const float* w2       = (const float*)d_in[16];
    const float* b2       = (const float*)d_in[17];
    const float* pix_w    = (const float*)d_in[18];
    const float* pix_b    = (const float*)d_in[19];

    const size_t TOK = (size_t)TOKENS * 768;
    float*  x    = (float*)d_ws;
    bf16_t* h    = (bf16_t*)(x + TOK);
    bf16_t* qbuf = h + TOK;
    bf16_t* wts  = qbuf + (size_t)TOKENS * 2304;
    size_t o = 0;
    bf16_t* patch_wT = wts + o; o += (size_t)768 * 768;
    bf16_t* wqkvT    = wts + o; o += (size_t)DEPTH * 2304 * 768;
    bf16_t* woT      = wts + o; o += (size_t)DEPTH * 768 * 768;
    bf16_t* w1T      = wts + o; o += (size_t)DEPTH * 3072 * 768;
    bf16_t* w2T      = wts + o; o += (size_t)DEPTH * 768 * 3072;
    bf16_t* pix_wT   = wts + o; o += (size_t)768 * 768;
    int* flags = (int*)(wts + o);
    int* midx  = flags + TOKENS;
    float* acc = (float*)(midx + MROWS);

    bf16_t* patches = qbuf;
    float*  pred    = (float*)qbuf;

    wconvT<<<dim3(768/32, 768/32, 1), 256, 0, stream>>>(patch_w, patch_wT, 768, 768);
    wconvT<<<dim3(2304/32, 768/32, DEPTH), 256, 0, stream>>>(wqkv, wqkvT, 768, 2304);
    wconvT<<<dim3(768/32, 768/32, DEPTH), 256, 0, stream>>>(wo, woT, 768, 768);
    wconvT<<<dim3(3072/32, 768/32, DEPTH), 256, 0, stream>>>(w1, w1T, 768, 3072);
    wconvT<<<dim3(768/32, 3072/32, DEPTH), 256, 0, stream>>>(w2, w2T, 3072, 768);
    wconvT<<<dim3(768/32, 768/32, 1), 256, 0, stream>>>(pix_w, pix_wT, 768, 768);

    patchify_kernel<<<TOKENS, 256, 0, stream>>>(img, patches);
    mask_kernel<<<BATCH, 256, 0, stream>>>(noise, flags, midx);

    mm64_bf16<0><<<dim3(768/64, TOKENS/64), 256, 0, stream>>>(
        patches, patch_wT, patch_b, nullptr, x, TOKENS, 768, 768);
    pe_mask_kernel<<<TOKENS/4, 256, 0, stream>>>(x, pos_emb, mask_tok, flags);

    for (int l = 0; l < DEPTH; ++l) {
        ln_kernel<<<TOKENS/4, 256, 0, stream>>>(x, h, ln1_s + l * 768, ln1_b + l * 768);
        mm_bf16<3><<<dim3(2304/128, TOKENS/128), 256, 0, stream>>>(
            h, wqkvT + (size_t)l * 2304 * 768, bqkv + l * 2304, nullptr, qbuf,
            TOKENS, 2304, 768);
        attn_kernel<<<BATCH * HEADS, 256, 0, stream>>>(qbuf, h);
        mm64_bf16<2><<<dim3(768/64, TOKENS/64), 256, 0, stream>>>(
            h, woT + (size_t)l * 768 * 768, bo + l * 768, x, x, TOKENS, 768, 768);
        ln_kernel<<<TOKENS/4, 256, 0, stream>>>(x, h, ln2_s + l * 768, ln2_b + l * 768);
        for (int ch = 0; ch < 2; ++ch) {
            bf16_t* hA = h + (size_t)ch * HALFROWS * 768;
            float*  xC = x + (size_t)ch * HALFROWS * 768;
            mm_bf16<1><<<dim3(MLPDIM/128, HALFROWS/128), 256, 0, stream>>>(
                hA, w1T + (size_t)l * 3072 * 768, b1 + l * MLPDIM, nullptr, qbuf,
                HALFROWS, MLPDIM, 768);
            mm64_bf16<2><<<dim3(768/64, HALFROWS/64), 256, 0, stream>>>(
                qbuf, w2T + (size_t)l * 768 * 3072, b2 + l * 768, xC, xC,
                HALFROWS, 768, MLPDIM);
        }
    }

    gather_kernel<<<MROWS, 256, 0, stream>>>(x, midx, h);
    mm64_bf16<0><<<dim3(768/64, MROWS/64), 256, 0, stream>>>(
        h, pix_wT, pix_b, nullptr, pred, MROWS, 768, 768);

    zero_kernel<<<1, 64, 0, stream>>>(acc);
    loss_kernel<<<4704, 256, 0, stream>>>(pred, img, midx, acc);
    finalize_kernel<<<1, 64, 0, stream>>>(acc, (float*)d_out);
}